// Round 1
// baseline (44177.631 us; speedup 1.0000x reference)
//
#include <hip/hip_runtime.h>

// ---------------------------------------------------------------------------
// Persistent-kernel LSTM (custom variant: relu g-gate, h = o*c, no tanh).
// B=128, S=1024, I=256, H=512, O=10.
//
// 8 independent batch-groups (16 rows each) x 32 CUs/group = 256 blocks.
// Each CU owns 16 h-columns; wave w (of 4) owns gate section w (i,f,g,o).
// W_hh / W_ih fragments live in VGPRs for the whole kernel.
// Cross-CU h exchange: double-buffered global bf16 buffer + monotone flags
// (signed >= spin; 0xAA ws poison is negative => safe).
// ---------------------------------------------------------------------------

#define GROUPS 8
#define BC     16      // batch rows per group
#define S_LEN  1024
#define I_DIM  256
#define H_DIM  512
#define HROW   544     // padded global h row stride (shorts) = 17*32
#define XPAD   264     // padded x tile row stride (shorts)

typedef float f32x4 __attribute__((ext_vector_type(4)));
typedef short s16x8 __attribute__((ext_vector_type(8)));

__device__ __forceinline__ unsigned short f2bf(float f) {
  unsigned u = __float_as_uint(f);
  u += 0x7fffu + ((u >> 16) & 1u);           // RNE
  return (unsigned short)(u >> 16);
}
__device__ __forceinline__ float bf2f(unsigned short h) {
  return __uint_as_float(((unsigned)h) << 16);
}
__device__ __forceinline__ float sigf(float x) {
  return 1.0f / (1.0f + __expf(-x));
}

__global__ __launch_bounds__(256, 1)
void lstm_persistent(const float* __restrict__ x,
                     const float* __restrict__ Wih,
                     const float* __restrict__ Whh,
                     const float* __restrict__ bih,
                     const float* __restrict__ bhh,
                     const float* __restrict__ fcw,
                     const float* __restrict__ fcb,
                     float* __restrict__ out,
                     int* __restrict__ flags,            // [GROUPS][32]
                     unsigned short* __restrict__ hbuf)  // [2][GROUPS][BC][HROW]
{
  __shared__ unsigned short x_s[2][BC][XPAD];  // x tile, double-buffered, bf16
  __shared__ float gates[4][BC][17];           // cross-wave gate exchange

  const int tid  = threadIdx.x;
  const int wave = tid >> 6;        // gate section 0..3 (i,f,g,o)
  const int lane = tid & 63;
  const int q    = lane >> 4;       // 0..3
  const int l15  = lane & 15;       // A-row (batch) / B-col (gate) / C-col
  const int bid  = blockIdx.x;
  const int g    = bid >> 5;        // group
  const int cu   = bid & 31;        // CU index within group

  // ---- persistent weight fragments in registers ----
  // B-frag layout (16x16x32 bf16): lane holds B[k=(l>>4)*8 + 0..7][n=l&15],
  // i.e. 8 contiguous k from row n of the [N][K] weight matrix.
  const int gcol = wave * H_DIM + cu * 16 + l15;   // global gate row 0..2047
  s16x8 bhh_f[16];
#pragma unroll
  for (int kb = 0; kb < 16; ++kb) {
    const float* src = Whh + (size_t)gcol * H_DIM + kb * 32 + q * 8;
    s16x8 v;
#pragma unroll
    for (int i = 0; i < 8; ++i) v[i] = (short)f2bf(src[i]);
    bhh_f[kb] = v;
  }
  s16x8 bih_f[8];
#pragma unroll
  for (int kb = 0; kb < 8; ++kb) {
    const float* src = Wih + (size_t)gcol * I_DIM + kb * 32 + q * 8;
    s16x8 v;
#pragma unroll
    for (int i = 0; i < 8; ++i) v[i] = (short)f2bf(src[i]);
    bih_f[kb] = v;
  }
  const float bias_v = bih[gcol] + bhh[gcol];

  // ---- preload x tile for t=0 into parity 0 ----
  {
    const int m = tid >> 4, kc = tid & 15;
    const float* src = x + ((size_t)(g * BC + m) * S_LEN + 0) * I_DIM + kc * 16;
    float xt[16];
    *(float4*)&xt[0]  = ((const float4*)src)[0];
    *(float4*)&xt[4]  = ((const float4*)src)[1];
    *(float4*)&xt[8]  = ((const float4*)src)[2];
    *(float4*)&xt[12] = ((const float4*)src)[3];
    s16x8 v0, v1;
#pragma unroll
    for (int i = 0; i < 8; ++i) { v0[i] = (short)f2bf(xt[i]); v1[i] = (short)f2bf(xt[8 + i]); }
    *(s16x8*)&x_s[0][m][kc * 16]     = v0;
    *(s16x8*)&x_s[0][m][kc * 16 + 8] = v1;
  }
  __syncthreads();

  const int half    = GROUPS * BC * HROW;       // shorts per parity buffer
  const int base_hs = g * (BC * HROW);
  int* gflags = flags + g * 32;

  int p = 0;
  float c_reg = 0.0f;   // c for (row = wave*4+q, col = l15)

  for (int t = 0; t < S_LEN; ++t) {
    // ---- x-part of gates (no h dependency: runs before the sync point) ----
    f32x4 acc = {bias_v, bias_v, bias_v, bias_v};
#pragma unroll
    for (int kb = 0; kb < 8; ++kb) {
      s16x8 a = *(const s16x8*)&x_s[p][l15][kb * 32 + q * 8];
      acc = __builtin_amdgcn_mfma_f32_16x16x32_bf16(a, bih_f[kb], acc, 0, 0, 0);
    }

    const bool pf = (t + 1 < S_LEN);
    const int m = tid >> 4, kc = tid & 15;
    float xt[16];

    if (t > 0) {
      // ---- wait for h_t ----
      const int fl = lane & 31;
      for (;;) {
        int v = __hip_atomic_load(&gflags[fl], __ATOMIC_RELAXED, __HIP_MEMORY_SCOPE_AGENT);
        if (__all(v >= t)) break;
        __builtin_amdgcn_s_sleep(1);
      }
      __threadfence();   // acquire: invalidate stale L1/L2 before h loads

      // issue next x slice loads now (drained at producer fence; overlapped)
      if (pf) {
        const float* src = x + ((size_t)(g * BC + m) * S_LEN + (t + 1)) * I_DIM + kc * 16;
        *(float4*)&xt[0]  = ((const float4*)src)[0];
        *(float4*)&xt[4]  = ((const float4*)src)[1];
        *(float4*)&xt[8]  = ((const float4*)src)[2];
        *(float4*)&xt[12] = ((const float4*)src)[3];
      }

      // ---- h-part: A-frags straight from global (L1 shares across waves) ----
      const unsigned short* hsrc =
          hbuf + (size_t)(t & 1) * half + base_hs + (size_t)l15 * HROW + q * 8;
      s16x8 afr[16];
#pragma unroll
      for (int kb = 0; kb < 16; ++kb) afr[kb] = *(const s16x8*)(hsrc + kb * 32);
#pragma unroll
      for (int kb = 0; kb < 16; ++kb)
        acc = __builtin_amdgcn_mfma_f32_16x16x32_bf16(afr[kb], bhh_f[kb], acc, 0, 0, 0);
    } else if (pf) {
      const float* src = x + ((size_t)(g * BC + m) * S_LEN + (t + 1)) * I_DIM + kc * 16;
      *(float4*)&xt[0]  = ((const float4*)src)[0];
      *(float4*)&xt[4]  = ((const float4*)src)[1];
      *(float4*)&xt[8]  = ((const float4*)src)[2];
      *(float4*)&xt[12] = ((const float4*)src)[3];
    }

    // ---- publish gate section to LDS (C/D: col=l&15, row=(l>>4)*4+r) ----
#pragma unroll
    for (int r = 0; r < 4; ++r) gates[wave][q * 4 + r][l15] = acc[r];
    __syncthreads();

    // ---- stash prefetched x into the other parity tile ----
    if (pf) {
      s16x8 v0, v1;
#pragma unroll
      for (int i = 0; i < 8; ++i) { v0[i] = (short)f2bf(xt[i]); v1[i] = (short)f2bf(xt[8 + i]); }
      *(s16x8*)&x_s[p ^ 1][m][kc * 16]     = v0;
      *(s16x8*)&x_s[p ^ 1][m][kc * 16 + 8] = v1;
    }

    // ---- elementwise gate update: wave handles rows wave*4 .. wave*4+3 ----
    {
      const int erow = wave * 4 + q;
      float yi = gates[0][erow][l15];
      float yf = gates[1][erow][l15];
      float yg = gates[2][erow][l15];
      float yo = gates[3][erow][l15];
      float ig = sigf(yi), fg = sigf(yf), gg = fmaxf(yg, 0.0f), og = sigf(yo);
      c_reg = fg * c_reg + ig * gg;
      float h = og * c_reg;
      hbuf[(size_t)((t + 1) & 1) * half + base_hs + (size_t)erow * HROW + cu * 16 + l15] =
          f2bf(h);
    }
    __threadfence();     // release: push h stores toward L3
    __syncthreads();
    if (tid == 0)
      __hip_atomic_store(&gflags[cu], t + 1, __ATOMIC_RELEASE, __HIP_MEMORY_SCOPE_AGENT);
    p ^= 1;
  }

  // ---- final FC: out[16,10] per group, done by cu==0 ----
  if (cu == 0) {
    const int fl = lane & 31;
    for (;;) {
      int v = __hip_atomic_load(&gflags[fl], __ATOMIC_RELAXED, __HIP_MEMORY_SCOPE_AGENT);
      if (__all(v >= S_LEN)) break;
      __builtin_amdgcn_s_sleep(1);
    }
    __threadfence();
    if (tid < BC * 10) {
      const int row = tid / 10, o = tid - row * 10;
      // h_S lives in parity (S & 1) == 0
      const unsigned short* hr = hbuf + base_hs + (size_t)row * HROW;
      const float* wr = fcw + (size_t)o * H_DIM;
      float sum = fcb[o];
      for (int k = 0; k < H_DIM; k += 8) {
        s16x8 h8 = *(const s16x8*)(hr + k);
#pragma unroll
        for (int j = 0; j < 8; ++j)
          sum += bf2f((unsigned short)h8[j]) * wr[k + j];
      }
      out[(g * BC + row) * 10 + o] = sum;
    }
  }
}

extern "C" void kernel_launch(void* const* d_in, const int* in_sizes, int n_in,
                              void* d_out, int out_size, void* d_ws, size_t ws_size,
                              hipStream_t stream) {
  (void)in_sizes; (void)n_in; (void)out_size; (void)ws_size;
  const float* x   = (const float*)d_in[0];
  const float* Wih = (const float*)d_in[1];
  const float* Whh = (const float*)d_in[2];
  const float* bih = (const float*)d_in[3];
  const float* bhh = (const float*)d_in[4];
  const float* fcw = (const float*)d_in[5];
  const float* fcb = (const float*)d_in[6];

  int* flags = (int*)d_ws;                                   // 8*32 ints, <4KB
  unsigned short* hbuf = (unsigned short*)((char*)d_ws + 4096);  // 2*8*16*544*2 B

  // flags must start < 1 (ws may be uninitialized on the first call)
  hipMemsetAsync(d_ws, 0, 4096, stream);

  hipLaunchKernelGGL(lstm_persistent, dim3(256), dim3(256), 0, stream,
                     x, Wih, Whh, bih, bhh, fcw, fcb, (float*)d_out, flags, hbuf);
}

// Round 2
// 4300.820 us; speedup vs baseline: 10.2719x; 10.2719x over previous
//
#include <hip/hip_runtime.h>

// ---------------------------------------------------------------------------
// Persistent-kernel LSTM (relu g-gate, h = o*c, no tanh).
// B=128, S=1024, I=256, H=512, O=10.
//
// 8 batch-groups x 32 CUs. Each CU owns 16 gate/h columns, waves own the
// 4 gate sections; W_ih/W_hh fragments pinned in VGPRs.
//
// R2 change: ZERO fences. h is exchanged as self-validating u32 words
// {step:16 | bf16:16} via RELAXED agent-scope atomics (coherent through L3,
// no buffer_wbl2 / buffer_inv in the loop). Consumers poll embedded
// counters; double-buffered by step parity. 0xAA poison => counter 0xAAAA,
// never matches, so no ws memset required.
// ---------------------------------------------------------------------------

#define GROUPS 8
#define BC     16
#define S_LEN  1024
#define I_DIM  256
#define H_DIM  512
#define XPAD   264            // x tile row stride (shorts)
#define HP     520            // h_lds row stride (shorts), keeps 16B alignment
#define HWORDS (BC * H_DIM)   // 8192 u32 per group per parity

typedef float f32x4 __attribute__((ext_vector_type(4)));
typedef short s16x8 __attribute__((ext_vector_type(8)));

__device__ __forceinline__ unsigned short f2bf(float f) {
  unsigned u = __float_as_uint(f);
  u += 0x7fffu + ((u >> 16) & 1u);           // RNE
  return (unsigned short)(u >> 16);
}
__device__ __forceinline__ float bf2f(unsigned short h) {
  return __uint_as_float(((unsigned)h) << 16);
}
__device__ __forceinline__ float sigf(float x) {
  return 1.0f / (1.0f + __expf(-x));
}

__global__ __launch_bounds__(256, 1)
void lstm_persistent(const float* __restrict__ x,
                     const float* __restrict__ Wih,
                     const float* __restrict__ Whh,
                     const float* __restrict__ bih,
                     const float* __restrict__ bhh,
                     const float* __restrict__ fcw,
                     const float* __restrict__ fcb,
                     float* __restrict__ out,
                     unsigned* __restrict__ hbuf)   // [2][GROUPS][BC][H_DIM] u32
{
  __shared__ unsigned short x_s[2][BC][XPAD];   // bf16 x tile, double-buffered
  __shared__ unsigned short h_lds[BC][HP];      // bf16 h tile for MFMA A-frags
  __shared__ float gates[4][BC][17];            // cross-wave gate exchange

  const int tid  = threadIdx.x;
  const int wave = tid >> 6;        // gate section 0..3 (i,f,g,o)
  const int lane = tid & 63;
  const int q    = lane >> 4;
  const int l15  = lane & 15;
  const int g    = blockIdx.x >> 5;
  const int cu   = blockIdx.x & 31;

  // ---- persistent weight fragments (B-frag: lane holds B[k=q*8+0..7][n=l15],
  // 8 contiguous k from row n of the [N][K] weight matrix) ----
  const int gcol = wave * H_DIM + cu * 16 + l15;   // gate row 0..2047
  s16x8 bhh_f[16];
#pragma unroll
  for (int kb = 0; kb < 16; ++kb) {
    const float* src = Whh + (size_t)gcol * H_DIM + kb * 32 + q * 8;
    s16x8 v;
#pragma unroll
    for (int i = 0; i < 8; ++i) v[i] = (short)f2bf(src[i]);
    bhh_f[kb] = v;
  }
  s16x8 bih_f[8];
#pragma unroll
  for (int kb = 0; kb < 8; ++kb) {
    const float* src = Wih + (size_t)gcol * I_DIM + kb * 32 + q * 8;
    s16x8 v;
#pragma unroll
    for (int i = 0; i < 8; ++i) v[i] = (short)f2bf(src[i]);
    bih_f[kb] = v;
  }
  const float bias_v = bih[gcol] + bhh[gcol];

  // ---- preload x tile for t=0 ----
  {
    const int m = tid >> 4, kc = tid & 15;
    const float* src = x + ((size_t)(g * BC + m) * S_LEN) * I_DIM + kc * 16;
    float xt[16];
    *(float4*)&xt[0]  = ((const float4*)src)[0];
    *(float4*)&xt[4]  = ((const float4*)src)[1];
    *(float4*)&xt[8]  = ((const float4*)src)[2];
    *(float4*)&xt[12] = ((const float4*)src)[3];
    s16x8 v0, v1;
#pragma unroll
    for (int i = 0; i < 8; ++i) { v0[i] = (short)f2bf(xt[i]); v1[i] = (short)f2bf(xt[8 + i]); }
    *(s16x8*)&x_s[0][m][kc * 16]     = v0;
    *(s16x8*)&x_s[0][m][kc * 16 + 8] = v1;
  }
  __syncthreads();

  unsigned* const ghb0 = hbuf + (size_t)g * HWORDS;            // parity 0
  unsigned* const ghb1 = hbuf + (size_t)(GROUPS + g) * HWORDS; // parity 1

  int p = 0;
  float c_reg = 0.0f;   // c for (row = wave*4+q, col = cu*16+l15)

  for (int t = 0; t < S_LEN; ++t) {
    const bool pf = (t + 1 < S_LEN);
    const int m = tid >> 4, kc = tid & 15;
    unsigned* const hb = (t & 1) ? ghb1 : ghb0;
    unsigned vals[32];
    float xt[16];

    // ---- issue h poll batch first (latency hidden behind x-part MFMAs) ----
    if (t > 0) {
#pragma unroll
      for (int i = 0; i < 32; ++i)
        vals[i] = __hip_atomic_load(hb + i * 256 + tid,
                                    __ATOMIC_RELAXED, __HIP_MEMORY_SCOPE_AGENT);
    }
    // ---- issue next x slice (cached loads, drained later) ----
    if (pf) {
      const float* src = x + ((size_t)(g * BC + m) * S_LEN + (t + 1)) * I_DIM + kc * 16;
      *(float4*)&xt[0]  = ((const float4*)src)[0];
      *(float4*)&xt[4]  = ((const float4*)src)[1];
      *(float4*)&xt[8]  = ((const float4*)src)[2];
      *(float4*)&xt[12] = ((const float4*)src)[3];
    }

    // ---- x-part of gates (no h dependency) ----
    f32x4 acc = {bias_v, bias_v, bias_v, bias_v};
#pragma unroll
    for (int kb = 0; kb < 8; ++kb) {
      s16x8 a = *(const s16x8*)&x_s[p][l15][kb * 32 + q * 8];
      acc = __builtin_amdgcn_mfma_f32_16x16x32_bf16(a, bih_f[kb], acc, 0, 0, 0);
    }

    if (t > 0) {
      // ---- poll embedded counters until all words carry step t ----
      const unsigned want = (unsigned)t;
      for (;;) {
        unsigned pend = 0;
#pragma unroll
        for (int i = 0; i < 32; ++i)
          if ((vals[i] >> 16) != want) pend |= (1u << i);
        if (pend == 0) break;
#pragma unroll
        for (int i = 0; i < 32; ++i)
          if (pend & (1u << i))
            vals[i] = __hip_atomic_load(hb + i * 256 + tid,
                                        __ATOMIC_RELAXED, __HIP_MEMORY_SCOPE_AGENT);
      }
      // ---- unpack bf16 payloads into LDS h tile ----
#pragma unroll
      for (int i = 0; i < 32; ++i) {
        const int w = i * 256 + tid;
        h_lds[w >> 9][w & 511] = (unsigned short)(vals[i] & 0xffffu);
      }
    }
    __syncthreads();

    if (t > 0) {
      // ---- h-part MFMAs from LDS ----
      s16x8 afr[16];
#pragma unroll
      for (int kb = 0; kb < 16; ++kb)
        afr[kb] = *(const s16x8*)&h_lds[l15][kb * 32 + q * 8];
#pragma unroll
      for (int kb = 0; kb < 16; ++kb)
        acc = __builtin_amdgcn_mfma_f32_16x16x32_bf16(afr[kb], bhh_f[kb], acc, 0, 0, 0);
    }

    // ---- publish gate section (C/D: col=l15, row=q*4+r) + stash next x ----
#pragma unroll
    for (int r = 0; r < 4; ++r) gates[wave][q * 4 + r][l15] = acc[r];
    if (pf) {
      s16x8 v0, v1;
#pragma unroll
      for (int i = 0; i < 8; ++i) { v0[i] = (short)f2bf(xt[i]); v1[i] = (short)f2bf(xt[8 + i]); }
      *(s16x8*)&x_s[p ^ 1][m][kc * 16]     = v0;
      *(s16x8*)&x_s[p ^ 1][m][kc * 16 + 8] = v1;
    }
    __syncthreads();

    // ---- elementwise update; each lane owns (row=wave*4+q, col=cu*16+l15) ----
    {
      const int erow = wave * 4 + q;
      float yi = gates[0][erow][l15];
      float yf = gates[1][erow][l15];
      float yg = gates[2][erow][l15];
      float yo = gates[3][erow][l15];
      float ig = sigf(yi), fg = sigf(yf), gg = fmaxf(yg, 0.0f), og = sigf(yo);
      c_reg = fg * c_reg + ig * gg;
      float h = og * c_reg;
      unsigned packv = (((unsigned)(t + 1)) << 16) | (unsigned)f2bf(h);
      unsigned* dst = ((t + 1) & 1) ? ghb1 : ghb0;
      __hip_atomic_store(dst + erow * H_DIM + cu * 16 + l15, packv,
                         __ATOMIC_RELAXED, __HIP_MEMORY_SCOPE_AGENT);
    }
    p ^= 1;
  }

  // ---- final FC (cu 0 of each group): h_S lives in parity 0, counter 1024 ----
  if (cu == 0) {
    unsigned vals[32];
#pragma unroll
    for (int i = 0; i < 32; ++i)
      vals[i] = __hip_atomic_load(ghb0 + i * 256 + tid,
                                  __ATOMIC_RELAXED, __HIP_MEMORY_SCOPE_AGENT);
    const unsigned want = (unsigned)S_LEN;
    for (;;) {
      unsigned pend = 0;
#pragma unroll
      for (int i = 0; i < 32; ++i)
        if ((vals[i] >> 16) != want) pend |= (1u << i);
      if (pend == 0) break;
#pragma unroll
      for (int i = 0; i < 32; ++i)
        if (pend & (1u << i))
          vals[i] = __hip_atomic_load(ghb0 + i * 256 + tid,
                                      __ATOMIC_RELAXED, __HIP_MEMORY_SCOPE_AGENT);
    }
#pragma unroll
    for (int i = 0; i < 32; ++i) {
      const int w = i * 256 + tid;
      h_lds[w >> 9][w & 511] = (unsigned short)(vals[i] & 0xffffu);
    }
    __syncthreads();

    if (tid < BC * 10) {
      const int row = tid / 10, o = tid - row * 10;
      const float* wr = fcw + (size_t)o * H_DIM;
      float sum = fcb[o];
      for (int k = 0; k < H_DIM; k += 8) {
#pragma unroll
        for (int j = 0; j < 8; ++j)
          sum += bf2f(h_lds[row][k + j]) * wr[k + j];
      }
      out[(g * BC + row) * 10 + o] = sum;
    }
  }
}

extern "C" void kernel_launch(void* const* d_in, const int* in_sizes, int n_in,
                              void* d_out, int out_size, void* d_ws, size_t ws_size,
                              hipStream_t stream) {
  (void)in_sizes; (void)n_in; (void)out_size; (void)ws_size;
  const float* x   = (const float*)d_in[0];
  const float* Wih = (const float*)d_in[1];
  const float* Whh = (const float*)d_in[2];
  const float* bih = (const float*)d_in[3];
  const float* bhh = (const float*)d_in[4];
  const float* fcw = (const float*)d_in[5];
  const float* fcb = (const float*)d_in[6];

  unsigned* hbuf = (unsigned*)d_ws;   // 2*8*8192*4 = 512 KB

  hipLaunchKernelGGL(lstm_persistent, dim3(256), dim3(256), 0, stream,
                     x, Wih, Whh, bih, bhh, fcw, fcb, (float*)d_out, hbuf);
}

// Round 4
// 3748.466 us; speedup vs baseline: 11.7855x; 1.1474x over previous
//
#include <hip/hip_runtime.h>
#include <stdint.h>

// ---------------------------------------------------------------------------
// Persistent-kernel LSTM (relu g-gate, h = o*c, no tanh).
// B=128, S=1024, I=256, H=512, O=10.
//
// R4: robust XCD-local exchange.
//  * Rendezvous: blocks publish XCC_ID; if dispatch is exactly 32/XCD, groups
//    are XCD-pure (group = physical XCD, slot = rank). Else: device-scope
//    (sc1/MALL) fallback protocol — slower but correct for ANY placement.
//  * Payload h buffer ROTATES over W step-slots: no address is ever re-read,
//    so plain loads can never hit a stale L1 line (pure path).
//  * Flags polled with global_atomic_add(0) (sc0 = return old): atomics
//    execute at the TCC (L2), never served by L1 -> always fresh, L2 latency.
//  * Producer release: plain h stores -> s_waitcnt vmcnt(0) (L2 ack) ->
//    barrier -> flag store (same L2). Impure path: all stores/loads sc1.
// ---------------------------------------------------------------------------

#define GROUPS 8
#define BC     16
#define S_LEN  1024
#define I_DIM  256
#define H_DIM  512
#define XPAD   264                    // x tile row stride (shorts)
#define HP     520                    // h_lds row stride (shorts)
#define FSTRIDE 16                    // flag stride (ints) = 64 B
#define PAYSLOT (GROUPS * BC * H_DIM) // shorts per rotation slot (128 KB)

typedef float f32x4 __attribute__((ext_vector_type(4)));
typedef short s16x8 __attribute__((ext_vector_type(8)));
typedef unsigned int u32x4 __attribute__((ext_vector_type(4)));

__device__ __forceinline__ unsigned short f2bf(float f) {
  unsigned u = __float_as_uint(f);
  u += 0x7fffu + ((u >> 16) & 1u);   // RNE
  return (unsigned short)(u >> 16);
}
__device__ __forceinline__ float bf2f(unsigned short h) {
  return __uint_as_float(((unsigned)h) << 16);
}
__device__ __forceinline__ float sigf(float x) { return 1.0f / (1.0f + __expf(-x)); }

// flag poll, XCD-local: atomic executes at TCC (L2), never served by L1
__device__ __forceinline__ int poll_local(uint64_t a) {
  int v;
  asm volatile("global_atomic_add %0, %1, %2, off sc0\n\ts_waitcnt vmcnt(0)"
               : "=v"(v) : "v"(a), "v"(0) : "memory");
  return v;
}
// device-scope (MALL) load / stores for the fallback path + rendezvous
__device__ __forceinline__ int ld_sc1(uint64_t a) {
  int v;
  asm volatile("global_load_dword %0, %1, off sc1\n\ts_waitcnt vmcnt(0)"
               : "=v"(v) : "v"(a) : "memory");
  return v;
}
__device__ __forceinline__ void st_sc1(uint64_t a, int v) {
  asm volatile("global_store_dword %0, %1, off sc1" :: "v"(a), "v"(v) : "memory");
}
__device__ __forceinline__ void st_short_sc1(uint64_t a, unsigned v) {
  asm volatile("global_store_short %0, %1, off sc1" :: "v"(a), "v"(v) : "memory");
}
__device__ __forceinline__ void ld64_sc1(uint64_t a, u32x4& p0, u32x4& p1,
                                         u32x4& p2, u32x4& p3) {
  asm volatile(
      "global_load_dwordx4 %0, %4, off sc1\n\t"
      "global_load_dwordx4 %1, %4, off offset:16 sc1\n\t"
      "global_load_dwordx4 %2, %4, off offset:32 sc1\n\t"
      "global_load_dwordx4 %3, %4, off offset:48 sc1\n\t"
      "s_waitcnt vmcnt(0)"
      : "=&v"(p0), "=&v"(p1), "=&v"(p2), "=&v"(p3)
      : "v"(a) : "memory");
}
__device__ __forceinline__ void drain_vm() {
  asm volatile("s_waitcnt vmcnt(0)" ::: "memory");
}

__global__ __launch_bounds__(256, 1)
void lstm_persistent(const float* __restrict__ x,
                     const float* __restrict__ Wih,
                     const float* __restrict__ Whh,
                     const float* __restrict__ bih,
                     const float* __restrict__ bhh,
                     const float* __restrict__ fcw,
                     const float* __restrict__ fcb,
                     float* __restrict__ out,
                     int* __restrict__ arrive,           // [1], zeroed
                     int* __restrict__ table,            // [256]
                     int* __restrict__ flags,            // [GROUPS][32][FSTRIDE]
                     unsigned short* __restrict__ hpay,  // [W][GROUPS][BC][H_DIM]
                     int wmask)
{
  __shared__ __align__(16) unsigned short x_s[2][BC][XPAD];
  __shared__ __align__(16) unsigned short h_lds[BC][HP];
  __shared__ __align__(16) float gates[4][BC][18];
  __shared__ int tbl[256];
  __shared__ int s_grp, s_slot, s_pure, s_abort;

  const int tid  = threadIdx.x;
  const int wave = tid >> 6;        // gate section 0..3 (i,f,g,o)
  const int lane = tid & 63;
  const int q    = lane >> 4;
  const int l15  = lane & 15;
  const int bid  = blockIdx.x;

  // ---- rendezvous: publish my XCD, wait for all 256, read the table ----
  const int xcd = __builtin_amdgcn_s_getreg((31u << 11) | 20) & 7;  // HW_REG_XCC_ID
  if (tid == 0) {
    s_abort = 0;
    st_sc1((uint64_t)&table[bid], xcd);
    drain_vm();
    atomicAdd(arrive, 1);
    while (atomicAdd(arrive, 0) < 256) __builtin_amdgcn_s_sleep(8);
  }
  __syncthreads();
  tbl[tid] = ld_sc1((uint64_t)&table[tid]) & 7;
  __syncthreads();
  if (tid == 0) {
    int cnt[8] = {0, 0, 0, 0, 0, 0, 0, 0};
    int slot = 0;
    for (int j = 0; j < 256; ++j) {
      if (j == bid) slot = cnt[xcd];
      cnt[tbl[j]]++;
    }
    bool ok = true;
    for (int k = 0; k < 8; ++k) ok &= (cnt[k] == 32);
    if (ok) { s_grp = xcd;     s_slot = slot;     s_pure = 1; }
    else    { s_grp = bid & 7; s_slot = bid >> 3; s_pure = 0; }
  }
  __syncthreads();
  const int  g    = s_grp;
  const int  slot = s_slot;
  const bool pure = (s_pure != 0);

  // ---- persistent weight fragments (B-frag: lane holds B[k=q*8+j][n=l15]) ----
  const int gcol = wave * H_DIM + slot * 16 + l15;   // gate row 0..2047
  s16x8 bhh_f[16];
#pragma unroll
  for (int kb = 0; kb < 16; ++kb) {
    const float* src = Whh + (size_t)gcol * H_DIM + kb * 32 + q * 8;
    s16x8 v;
#pragma unroll
    for (int i = 0; i < 8; ++i) v[i] = (short)f2bf(src[i]);
    bhh_f[kb] = v;
  }
  s16x8 bih_f[8];
#pragma unroll
  for (int kb = 0; kb < 8; ++kb) {
    const float* src = Wih + (size_t)gcol * I_DIM + kb * 32 + q * 8;
    s16x8 v;
#pragma unroll
    for (int i = 0; i < 8; ++i) v[i] = (short)f2bf(src[i]);
    bih_f[kb] = v;
  }
  const float bias_v = bih[gcol] + bhh[gcol];

  // ---- preload x tile t=0 ----
  {
    const int m = tid >> 4, kc = tid & 15;
    const float* src = x + ((size_t)(g * BC + m) * S_LEN) * I_DIM + kc * 16;
    float xt[16];
    *(float4*)&xt[0]  = ((const float4*)src)[0];
    *(float4*)&xt[4]  = ((const float4*)src)[1];
    *(float4*)&xt[8]  = ((const float4*)src)[2];
    *(float4*)&xt[12] = ((const float4*)src)[3];
    s16x8 v0, v1;
#pragma unroll
    for (int i = 0; i < 8; ++i) { v0[i] = (short)f2bf(xt[i]); v1[i] = (short)f2bf(xt[8 + i]); }
    *(s16x8*)&x_s[0][m][kc * 16]     = v0;
    *(s16x8*)&x_s[0][m][kc * 16 + 8] = v1;
  }
  __syncthreads();

  const size_t   gpay  = (size_t)g * (BC * H_DIM);   // shorts, within a slot
  int* const     fgrp  = flags + (size_t)g * 32 * FSTRIDE;
  const uint64_t fpoll = (uint64_t)(fgrp + (size_t)(lane & 31) * FSTRIDE);
  int* const     fmine = fgrp + (size_t)slot * FSTRIDE;

  int p = 0;
  float c_reg = 0.0f;   // c for (row = wave*4+q, col = slot*16+l15)

  for (int t = 0; t < S_LEN; ++t) {
    const bool pf = (t + 1 < S_LEN);
    const int m = tid >> 4, kc = tid & 15;

    // ---- issue next x slice (plain cached loads) ----
    float xt[16];
    if (pf) {
      const float* src = x + ((size_t)(g * BC + m) * S_LEN + (t + 1)) * I_DIM + kc * 16;
      *(float4*)&xt[0]  = ((const float4*)src)[0];
      *(float4*)&xt[4]  = ((const float4*)src)[1];
      *(float4*)&xt[8]  = ((const float4*)src)[2];
      *(float4*)&xt[12] = ((const float4*)src)[3];
    }

    // ---- x-part of gates ----
    f32x4 acc = {bias_v, bias_v, bias_v, bias_v};
#pragma unroll
    for (int kb = 0; kb < 8; ++kb) {
      s16x8 a = *(const s16x8*)&x_s[p][l15][kb * 32 + q * 8];
      acc = __builtin_amdgcn_mfma_f32_16x16x32_bf16(a, bih_f[kb], acc, 0, 0, 0);
    }

    // ---- stash next x into other parity ----
    if (pf) {
      s16x8 v0, v1;
#pragma unroll
      for (int i = 0; i < 8; ++i) { v0[i] = (short)f2bf(xt[i]); v1[i] = (short)f2bf(xt[8 + i]); }
      *(s16x8*)&x_s[p ^ 1][m][kc * 16]     = v0;
      *(s16x8*)&x_s[p ^ 1][m][kc * 16 + 8] = v1;
    }

    if (t > 0) {
      // ---- wait for h_t: all 32 per-CU flags >= t ----
      if (wave == 0 && !s_abort) {
        int rounds = 0;
        for (;;) {
          int fv = pure ? poll_local(fpoll) : ld_sc1(fpoll);
          if (__all(fv >= t)) break;
          if (!pure) __builtin_amdgcn_s_sleep(2);
          if (++rounds > (1 << 15)) { if (lane == 0) s_abort = 1; break; }
        }
      }
      __syncthreads();                                        // B1
      // ---- bulk payload load from rotation slot t ----
      const size_t pb = (size_t)(t & wmask) * PAYSLOT + gpay + (size_t)tid * 32;
      u32x4 p0, p1, p2, p3;
      if (pure) {
        const u32x4* srcv = (const u32x4*)(hpay + pb);
        p0 = srcv[0]; p1 = srcv[1]; p2 = srcv[2]; p3 = srcv[3];
      } else {
        ld64_sc1((uint64_t)(hpay + pb), p0, p1, p2, p3);
      }
      unsigned short* dst = &h_lds[tid >> 4][(tid & 15) * 32];
      ((u32x4*)dst)[0] = p0; ((u32x4*)dst)[1] = p1;
      ((u32x4*)dst)[2] = p2; ((u32x4*)dst)[3] = p3;
      __syncthreads();                                        // B2
      // ---- h-part MFMAs: two interleaved chains ----
      f32x4 h0 = {0.f, 0.f, 0.f, 0.f}, h1 = {0.f, 0.f, 0.f, 0.f};
#pragma unroll
      for (int kb = 0; kb < 16; kb += 2) {
        s16x8 a0 = *(const s16x8*)&h_lds[l15][kb * 32 + q * 8];
        s16x8 a1 = *(const s16x8*)&h_lds[l15][(kb + 1) * 32 + q * 8];
        h0 = __builtin_amdgcn_mfma_f32_16x16x32_bf16(a0, bhh_f[kb], h0, 0, 0, 0);
        h1 = __builtin_amdgcn_mfma_f32_16x16x32_bf16(a1, bhh_f[kb + 1], h1, 0, 0, 0);
      }
      acc += h0 + h1;
    } else {
      __syncthreads();                                        // match B1
      __syncthreads();                                        // match B2
    }

    // ---- publish gate section (C/D: col=l15, row=q*4+r) ----
#pragma unroll
    for (int r = 0; r < 4; ++r) gates[wave][q * 4 + r][l15] = acc[r];
    __syncthreads();                                          // B3

    // ---- elementwise; lane owns (row=wave*4+q, col=slot*16+l15) ----
    {
      const int erow = wave * 4 + q;
      float yi = gates[0][erow][l15];
      float yf = gates[1][erow][l15];
      float yg = gates[2][erow][l15];
      float yo = gates[3][erow][l15];
      float ig = sigf(yi), fg = sigf(yf), gg = fmaxf(yg, 0.0f), og = sigf(yo);
      c_reg = fg * c_reg + ig * gg;
      float h = og * c_reg;
      const size_t hi = (size_t)((t + 1) & wmask) * PAYSLOT + gpay +
                        (size_t)erow * H_DIM + slot * 16 + l15;
      unsigned hv = (unsigned)f2bf(h);
      if (pure) hpay[hi] = (unsigned short)hv;
      else      st_short_sc1((uint64_t)&hpay[hi], hv);
    }
    drain_vm();           // h stores ack'd (L2 pure / MALL impure)
    __syncthreads();      // B4: whole block drained
    if (tid == 0) {
      if (pure) *fmine = t + 1;
      else      st_sc1((uint64_t)fmine, t + 1);
    }
    p ^= 1;
  }

  // ---- final FC: slot-0 block per group; h_S in rotation slot 0 ----
  if (slot == 0) {
    if (wave == 0 && !s_abort) {
      int rounds = 0;
      for (;;) {
        int fv = pure ? poll_local(fpoll) : ld_sc1(fpoll);
        if (__all(fv >= S_LEN)) break;
        if (!pure) __builtin_amdgcn_s_sleep(2);
        if (++rounds > (1 << 15)) break;
      }
    }
    __syncthreads();
    const size_t pb = gpay + (size_t)tid * 32;   // slot (S_LEN & wmask) == 0
    u32x4 p0, p1, p2, p3;
    if (pure) {
      const u32x4* srcv = (const u32x4*)(hpay + pb);
      p0 = srcv[0]; p1 = srcv[1]; p2 = srcv[2]; p3 = srcv[3];
    } else {
      ld64_sc1((uint64_t)(hpay + pb), p0, p1, p2, p3);
    }
    unsigned short* dst = &h_lds[tid >> 4][(tid & 15) * 32];
    ((u32x4*)dst)[0] = p0; ((u32x4*)dst)[1] = p1;
    ((u32x4*)dst)[2] = p2; ((u32x4*)dst)[3] = p3;
    __syncthreads();

    if (tid < BC * 10) {
      const int row = tid / 10, o = tid - row * 10;
      const float* wr = fcw + (size_t)o * H_DIM;
      float sum = fcb[o];
      for (int k = 0; k < H_DIM; k += 8) {
#pragma unroll
        for (int j = 0; j < 8; ++j)
          sum += bf2f(h_lds[row][k + j]) * wr[k + j];
      }
      out[(g * BC + row) * 10 + o] = sum;
    }
  }
}

extern "C" void kernel_launch(void* const* d_in, const int* in_sizes, int n_in,
                              void* d_out, int out_size, void* d_ws, size_t ws_size,
                              hipStream_t stream) {
  (void)in_sizes; (void)n_in; (void)out_size;
  const float* x   = (const float*)d_in[0];
  const float* Wih = (const float*)d_in[1];
  const float* Whh = (const float*)d_in[2];
  const float* bih = (const float*)d_in[3];
  const float* bhh = (const float*)d_in[4];
  const float* fcw = (const float*)d_in[5];
  const float* fcb = (const float*)d_in[6];

  int* arrive = (int*)d_ws;                          // @0
  int* table  = (int*)((char*)d_ws + 4096);          // @4K, 256 ints
  int* flags  = (int*)((char*)d_ws + 8192);          // @8K, 8*32*16 ints = 16 KB
  unsigned short* hpay = (unsigned short*)((char*)d_ws + 32768);   // @32K

  // rotation depth W (power of two, 2..64) sized to the workspace
  size_t avail = ws_size > 32768 ? ws_size - 32768 : 0;
  int W = 2;
  while (W < 64 && (size_t)(W * 2) * (PAYSLOT * 2) <= avail) W <<= 1;

  // arrive counter must start at 0; flags poison (0xAA..) is negative -> safe
  hipMemsetAsync(d_ws, 0, 4096, stream);

  hipLaunchKernelGGL(lstm_persistent, dim3(256), dim3(256), 0, stream,
                     x, Wih, Whh, bih, bhh, fcw, fcb, (float*)d_out,
                     arrive, table, flags, hpay, W - 1);
}